// Round 11
// baseline (636.648 us; speedup 1.0000x reference)
//
#include <hip/hip_runtime.h>
#include <math.h>

// Radial NUFFT + Pipe-Menon density compensation, MI355X (gfx950).
// bf16 MFMA (16x16x32), 2-term hi/lo split (3 products). Round 11: adjoint is
// a PURE GEMM — E = conj(A)*d is materialized per-iteration by ebuild_k
// (sincos from traj, packed bf16 hi/lo, r9-verified chunk layout), so the adj
// K-loop has no LDS, no sincos, no staging registers: 12 coalesced frag loads
// + 54 MFMA per chunk. Target: arch-VGPR small enough for 3-4 waves/SIMD.

#define MTOT 36864      // N_SHOTS*N_SAMPLES == NPIX*NPIX
#define NPIX 192
#define SPLITS 256
#define MPS (MTOT / SPLITS)     // 144 m per split
#define ADJ_CHUNKS (MPS / 16)   // 9 chunks of 16 m (32 K) per split
#define PG 4                    // partial output images

typedef __attribute__((ext_vector_type(8))) short s16x8;
typedef __attribute__((ext_vector_type(4))) float f32x4;
typedef __attribute__((ext_vector_type(4))) unsigned u32x4;

__device__ __forceinline__ f32x4 mfma_bf16(u32x4 a, u32x4 b, f32x4 c) {
    return __builtin_amdgcn_mfma_f32_16x16x32_bf16(
        __builtin_bit_cast(s16x8, a), __builtin_bit_cast(s16x8, b), c, 0, 0, 0);
}

// Split (a,b) into packed bf16 pairs: hi = (bf16(a) | bf16(b)<<16), lo = residuals.
__device__ __forceinline__ void split_pk(float a, float b, unsigned &hi, unsigned &lo) {
    const unsigned ua = __float_as_uint(a), ub = __float_as_uint(b);
    const unsigned ha = (ua + 0x8000u) & 0xffff0000u;
    const unsigned hb = (ub + 0x8000u) & 0xffff0000u;
    hi = (ha >> 16) | hb;
    const float la = a - __uint_as_float(ha);
    const float lb = b - __uint_as_float(hb);
    lo = ((__float_as_uint(la) + 0x8000u) >> 16) |
         ((__float_as_uint(lb) + 0x8000u) & 0xffff0000u);
}

// k split into 12-bit hi + residual so kh*p (p integer, |p|<=96) is EXACT in fp32.
__device__ __forceinline__ void ksplit(float k, float &kh, float &kl) {
    kh = __uint_as_float(__float_as_uint(k) & 0xfffff000u);
    kl = k - kh;
}
__device__ __forceinline__ float redphase(float kh, float kl, float p) {
    float r = kh * p;
    r -= rintf(r);
    r = fmaf(kl, p, r);
    return r;                   // revolutions, |r| <= ~0.512
}
__device__ __forceinline__ unsigned rot16(unsigned v) {
    return __builtin_amdgcn_alignbit(v, v, 16);
}

// ---------------------------------------------------------------------------
// Precompute packed B phasor (cos, -sin) hi/lo, CHUNK-CONTIGUOUS layout
// (r9-verified, no swizzle): PS[mc][plane][c(192)][mi(16)].
__global__ void precompP_k(const float* __restrict__ traj, const int comp,
                           unsigned* __restrict__ PS) {
    const int m = blockIdx.x * 256 + threadIdx.x;
    const int c = blockIdx.y;
    float kh, kl; ksplit(traj[2 * m + comp], kh, kl);
    const float ph = redphase(kh, kl, (float)(c - 96));
    const float co = __builtin_amdgcn_cosf(ph);
    const float si = __builtin_amdgcn_sinf(ph);
    unsigned h, l; split_pk(co, -si, h, l);
    const int mc = m >> 4, mi = m & 15;
    PS[(size_t)mc * 6144 + c * 16 + mi]        = h;
    PS[(size_t)mc * 6144 + 3072 + c * 16 + mi] = l;
}

// E[m,x] = conj(A[m,x]) * d[m], packed bf16 hi/lo, same chunk layout.
// conj(A) = (cos, +sin); Er = c*dr - s*di, Ei = c*di + s*dr (r8-verified math).
__global__ void ebuild_k(const float* __restrict__ traj,
                         const float* __restrict__ dr, const float* __restrict__ di,
                         unsigned* __restrict__ ES) {
    const int m = blockIdx.x * 256 + threadIdx.x;
    const int c = blockIdx.y;                        // x coordinate
    float kh, kl; ksplit(traj[2 * m], kh, kl);
    const float ph = redphase(kh, kl, (float)(c - 96));
    const float co = __builtin_amdgcn_cosf(ph);
    const float si = __builtin_amdgcn_sinf(ph);
    const float dr_ = dr[m], di_ = di[m];
    const float Er = co * dr_ - si * di_;
    const float Ei = co * di_ + si * dr_;
    unsigned h, l; split_pk(Er, Ei, h, l);
    const int mc = m >> 4, mi = m & 15;
    ES[(size_t)mc * 6144 + c * 16 + mi]        = h;
    ES[(size_t)mc * 6144 + 3072 + c * 16 + mi] = l;
}

__global__ void winit_k(float* __restrict__ wr, float* __restrict__ wi) {
    const int m = blockIdx.x * 256 + threadIdx.x;
    wr[m] = 1.f; wi[m] = 0.f;
}

// ---------------------------------------------------------------------------
// Adjoint pure GEMM: out[x,y] += sum_m E[m,x]*conj(B[m,y]).
// Block: 4 waves (2x2 of 48x48) = 96x x 96y quarter; grid (4, 256) = 1024
// blocks. NO LDS, NO staging: direct coalesced u32x4 frag loads per chunk
// (r9-verified offsets), 54 MFMA per chunk. Epilogue: PG=4 partial atomics.
__global__ __launch_bounds__(256) void adj_gemm_k(
    const unsigned* __restrict__ ES, const unsigned* __restrict__ BS,
    float* __restrict__ outP)
{
    const int tid = threadIdx.x;
    const int lane = tid & 63, wid = tid >> 6;     // wid 0..3
    const int l15 = lane & 15, qd = lane >> 4;
    const int bx = blockIdx.x & 1, by = blockIdx.x >> 1;
    const int wi = wid & 1, wj = wid >> 1;
    const int s = blockIdx.y;                      // split 0..255
    float* outRe = outP + (size_t)(s & (PG - 1)) * (2 * MTOT);
    float* outIm = outRe + MTOT;

    f32x4 accRe[3][3], accIm[3][3];
    #pragma unroll
    for (int i = 0; i < 3; ++i)
        #pragma unroll
        for (int j = 0; j < 3; ++j) {
            accRe[i][j] = (f32x4){0.f, 0.f, 0.f, 0.f};
            accIm[i][j] = (f32x4){0.f, 0.f, 0.f, 0.f};
        }

    int aoff[3], boff[3];                          // r9-verified fragment offsets
    #pragma unroll
    for (int t = 0; t < 3; ++t) {
        aoff[t] = (bx * 96 + wi * 48 + t * 16 + l15) * 16 + qd * 4;
        boff[t] = (by * 96 + wj * 48 + t * 16 + l15) * 16 + qd * 4;
    }
    const unsigned* Eb = ES + (size_t)(s * ADJ_CHUNKS) * 6144;
    const unsigned* Bb = BS + (size_t)(s * ADJ_CHUNKS) * 6144;

    for (int ch = 0; ch < ADJ_CHUNKS; ++ch) {
        const unsigned* Ec = Eb + (size_t)ch * 6144;
        const unsigned* Bc = Bb + (size_t)ch * 6144;
        u32x4 Eh[3], El[3];
        #pragma unroll
        for (int t = 0; t < 3; ++t) {
            Eh[t] = *(const u32x4*)(Ec + aoff[t]);
            El[t] = *(const u32x4*)(Ec + 3072 + aoff[t]);
        }
        #pragma unroll
        for (int sj = 0; sj < 3; ++sj) {
            const u32x4 Ph = *(const u32x4*)(Bc + boff[sj]);          // (cb, -sb)
            const u32x4 Pl = *(const u32x4*)(Bc + 3072 + boff[sj]);
            u32x4 Qh, Ql;
            #pragma unroll
            for (int r = 0; r < 4; ++r) {
                Qh[r] = rot16(Ph[r]) ^ 0x00008000u;                   // (sb, cb)
                Ql[r] = rot16(Pl[r]) ^ 0x00008000u;
            }
            #pragma unroll
            for (int si = 0; si < 3; ++si) {
                accRe[si][sj] = mfma_bf16(Eh[si], Ph, accRe[si][sj]);
                accRe[si][sj] = mfma_bf16(Eh[si], Pl, accRe[si][sj]);
                accRe[si][sj] = mfma_bf16(El[si], Ph, accRe[si][sj]);
                accIm[si][sj] = mfma_bf16(Eh[si], Qh, accIm[si][sj]);
                accIm[si][sj] = mfma_bf16(Eh[si], Ql, accIm[si][sj]);
                accIm[si][sj] = mfma_bf16(El[si], Qh, accIm[si][sj]);
            }
        }
    }

    // epilogue: direct global atomics into partial image (r8-verified mapping)
    #pragma unroll
    for (int si = 0; si < 3; ++si)
        #pragma unroll
        for (int sj = 0; sj < 3; ++sj)
            #pragma unroll
            for (int rg = 0; rg < 4; ++rg) {
                const int x = bx * 96 + wi * 48 + si * 16 + qd * 4 + rg;  // C/D row
                const int y = by * 96 + wj * 48 + sj * 16 + l15;          // C/D col
                atomicAdd(outRe + x * NPIX + y, accRe[si][sj][rg]);
                atomicAdd(outIm + x * NPIX + y, accIm[si][sj][rg]);
            }
}

// ---------------------------------------------------------------------------
// fwdq: q[m] = sum_x A[m,x] * (sum_y B[m,y]*g[x,y]).   (unchanged from r5)
__device__ __forceinline__ void fw_stage_load(const unsigned* __restrict__ Ghi,
                                              const unsigned* __restrict__ Glo,
                                              int tid, int koff, u32x4 st[3]) {
    #pragma unroll
    for (int j = 0; j < 3; ++j) {
        const int li = tid + j * 576;
        if (li < 1536) {
            const int row = li >> 3, pl = (li >> 2) & 1, qt = li & 3;
            const unsigned* src = pl ? Glo : Ghi;
            st[j] = *(const u32x4*)(src + row * 192 + koff + qt * 4);
        }
    }
}
__device__ __forceinline__ void fw_stage_write(unsigned* sb, int tid, const u32x4 st[3]) {
    #pragma unroll
    for (int j = 0; j < 3; ++j) {
        const int li = tid + j * 576;
        if (li < 1536) {
            const int row = li >> 3, pl = (li >> 2) & 1, qt = li & 3;
            *(u32x4*)(sb + pl * 3840 + row * 20 + qt * 4) = st[j];
        }
    }
}

__global__ __launch_bounds__(576) void fwdq_k(
    const float* __restrict__ traj,
    const unsigned* __restrict__ Ghi, const unsigned* __restrict__ Glo,
    float* __restrict__ wre, float* __restrict__ wim,
    const int mode,
    float* __restrict__ qre, float* __restrict__ qim)
{
    __shared__ unsigned sG[2][2 * 3840];   // 60 KB
    const int tid = threadIdx.x;
    const int lane = tid & 63, wid = tid >> 6;         // wid 0..8
    const int l15 = lane & 15, q = lane >> 4;
    const int m = (blockIdx.x * 9 + wid) * 16 + l15;
    const float2 kk = *(const float2*)(traj + 2 * m);
    float kxh, kxl, kyh, kyl;
    ksplit(kk.x, kxh, kxl);
    ksplit(kk.y, kyh, kyl);

    f32x4 tre[12], tim[12];
    #pragma unroll
    for (int i = 0; i < 12; ++i) {
        tre[i] = (f32x4){0.f, 0.f, 0.f, 0.f};
        tim[i] = (f32x4){0.f, 0.f, 0.f, 0.f};
    }

    float bc, bs;
    { const float ph = redphase(kyh, kyl, (float)(q * 4 - 96)); 
      bc = __builtin_amdgcn_cosf(ph); bs = __builtin_amdgcn_sinf(ph); }
    const float r1c = __builtin_amdgcn_cosf(kk.y), r1s = __builtin_amdgcn_sinf(kk.y);
    float r16c, r16s;
    { float g = kk.y * 16.f; g -= rintf(g);
      r16c = __builtin_amdgcn_cosf(g); r16s = __builtin_amdgcn_sinf(g); }

    u32x4 st[3];
    fw_stage_load(Ghi, Glo, tid, 0, st);
    fw_stage_write(&sG[0][0], tid, st);
    __syncthreads();

    for (int ch = 0; ch < 12; ++ch) {
        if (ch < 11) fw_stage_load(Ghi, Glo, tid, (ch + 1) * 16, st);

        u32x4 Ph, Pl, Qh, Ql;
        {
            float c = bc, s = bs;
            #pragma unroll
            for (int r = 0; r < 4; ++r) {
                unsigned h, l; split_pk(c, s, h, l);
                Ph[r] = h; Pl[r] = l;
                Qh[r] = rot16(h) ^ 0x00008000u;
                Ql[r] = rot16(l) ^ 0x00008000u;
                const float nc = c * r1c - s * r1s, ns = s * r1c + c * r1s;
                c = nc; s = ns;
            }
            const float nbc = bc * r16c - bs * r16s, nbs = bs * r16c + bc * r16s;
            bc = nbc; bs = nbs;
        }

        const unsigned* sb = &sG[ch & 1][0];
        #pragma unroll
        for (int si = 0; si < 12; ++si) {
            const int base = (si * 16 + l15) * 20 + q * 4;
            const u32x4 gh = *(const u32x4*)(sb + base);
            const u32x4 gl = *(const u32x4*)(sb + 3840 + base);
            tre[si] = mfma_bf16(gh, Ph, tre[si]);
            tre[si] = mfma_bf16(gh, Pl, tre[si]);
            tre[si] = mfma_bf16(gl, Ph, tre[si]);
            tim[si] = mfma_bf16(gh, Qh, tim[si]);
            tim[si] = mfma_bf16(gh, Ql, tim[si]);
            tim[si] = mfma_bf16(gl, Qh, tim[si]);
        }

        if (ch < 11) {
            __syncthreads();
            fw_stage_write(&sG[(ch + 1) & 1][0], tid, st);
            __syncthreads();
        }
    }

    float qr = 0.f, qi = 0.f;
    {
        float g = kk.x * 16.f; g -= rintf(g);
        const float rc = __builtin_amdgcn_cosf(g), rs = __builtin_amdgcn_sinf(g);
        #pragma unroll
        for (int rg = 0; rg < 4; ++rg) {
            const float ph = redphase(kxh, kxl, (float)(q * 4 + rg - 96));
            float c = __builtin_amdgcn_cosf(ph), s = __builtin_amdgcn_sinf(ph);
            #pragma unroll
            for (int si = 0; si < 12; ++si) {
                const float tr = tre[si][rg], ti = tim[si][rg];
                qr += c * tr + s * ti;
                qi += c * ti - s * tr;
                const float nc = c * rc - s * rs, ns = s * rc + c * rs;
                c = nc; s = ns;
            }
        }
    }
    qr += __shfl_xor(qr, 16); qi += __shfl_xor(qi, 16);
    qr += __shfl_xor(qr, 32); qi += __shfl_xor(qi, 32);
    if (lane < 16) {
        if (mode == 0) {
            const float den = fmaxf(sqrtf(qr * qr + qi * qi), 1e-20f);
            wre[m] /= den; wim[m] /= den;
        } else {
            const float sc = sqrtf(wre[m] * wre[m] + wim[m] * wim[m]);
            qre[m] = qr * sc; qim[m] = qi * sc;
        }
    }
}

// ---------------------------------------------------------------------------
__global__ void presplit_k(const float* __restrict__ re, const float* __restrict__ im,
                           unsigned* __restrict__ Gh, unsigned* __restrict__ Gl) {
    const int e = blockIdx.x * 256 + threadIdx.x;
    unsigned h, l;
    split_pk(re[e], im[e], h, l);     // low16 = re (even K), high16 = im (odd K)
    Gh[e] = h; Gl[e] = l;
}

// Reduce PG partial images + presplit (pipe path)
__global__ void presplitP_k(const float* __restrict__ outP,
                            unsigned* __restrict__ Gh, unsigned* __restrict__ Gl) {
    const int e = blockIdx.x * 256 + threadIdx.x;
    float re = 0.f, im = 0.f;
    #pragma unroll
    for (int g = 0; g < PG; ++g) {
        re += outP[(size_t)g * (2 * MTOT) + e];
        im += outP[(size_t)g * (2 * MTOT) + MTOT + e];
    }
    unsigned h, l;
    split_pk(re, im, h, l);
    Gh[e] = h; Gl[e] = l;
}

// Reduce PG partial images -> final output
__global__ void reduceOut_k(const float* __restrict__ outP, float* __restrict__ out) {
    const int e = blockIdx.x * 256 + threadIdx.x;
    float re = 0.f, im = 0.f;
    #pragma unroll
    for (int g = 0; g < PG; ++g) {
        re += outP[(size_t)g * (2 * MTOT) + e];
        im += outP[(size_t)g * (2 * MTOT) + MTOT + e];
    }
    out[e] = re; out[MTOT + e] = im;
}

// ---------------------------------------------------------------------------
extern "C" void kernel_launch(void* const* d_in, const int* in_sizes, int n_in,
                              void* d_out, int out_size, void* d_ws, size_t ws_size,
                              hipStream_t stream)
{
    const float* xin  = (const float*)d_in[0];   // (2,192,192)
    const float* traj = (const float*)d_in[1];   // (36864,2)
    float* out = (float*)d_out;                  // (2,192,192)

    char* pb = (char*)d_ws;
    unsigned* BS = (unsigned*)pb; pb += (size_t)2304 * 6144 * 4;   // 56.6 MB
    unsigned* ES = (unsigned*)pb; pb += (size_t)2304 * 6144 * 4;   // 56.6 MB
    float* outP = (float*)pb; pb += (size_t)PG * 2 * MTOT * 4;
    float* wr   = (float*)pb; pb += MTOT * 4;
    float* wi   = (float*)pb; pb += MTOT * 4;
    float* dre  = (float*)pb; pb += MTOT * 4;
    float* dim_ = (float*)pb; pb += MTOT * 4;
    unsigned* Ghi = (unsigned*)pb; pb += MTOT * 4;
    unsigned* Glo = (unsigned*)pb; pb += MTOT * 4;

    precompP_k<<<dim3(MTOT / 256, NPIX), 256, 0, stream>>>(traj, 1, BS);
    winit_k<<<MTOT / 256, 256, 0, stream>>>(wr, wi);

    for (int it = 0; it < 3; ++it) {
        hipMemsetAsync(outP, 0, (size_t)PG * 2 * MTOT * 4, stream);
        ebuild_k<<<dim3(MTOT / 256, NPIX), 256, 0, stream>>>(traj, wr, wi, ES);
        adj_gemm_k<<<dim3(4, SPLITS), 256, 0, stream>>>(ES, BS, outP);
        presplitP_k<<<MTOT / 256, 256, 0, stream>>>(outP, Ghi, Glo);
        fwdq_k<<<256, 576, 0, stream>>>(traj, Ghi, Glo, wr, wi, 0, dre, dim_);
    }

    presplit_k<<<MTOT / 256, 256, 0, stream>>>(xin, xin + MTOT, Ghi, Glo);
    fwdq_k<<<256, 576, 0, stream>>>(traj, Ghi, Glo, wr, wi, 1, dre, dim_);
    hipMemsetAsync(outP, 0, (size_t)PG * 2 * MTOT * 4, stream);
    ebuild_k<<<dim3(MTOT / 256, NPIX), 256, 0, stream>>>(traj, dre, dim_, ES);
    adj_gemm_k<<<dim3(4, SPLITS), 256, 0, stream>>>(ES, BS, outP);
    reduceOut_k<<<MTOT / 256, 256, 0, stream>>>(outP, out);
}

// Round 12
// 606.036 us; speedup vs baseline: 1.0505x; 1.0505x over previous
//
#include <hip/hip_runtime.h>
#include <math.h>

// Radial NUFFT + Pipe-Menon density compensation, MI355X (gfx950).
// bf16 MFMA (16x16x32), 2-term hi/lo split (3 products). Round 12 = round 11
// (pure-GEMM adjoint w/ E-table) with ONE change: adj wave tile 48x48 -> 32x32
// (acc 72 -> 32 AGPRs) for 5 waves/SIMD occupancy; SPLITS 256 -> 128.

#define MTOT 36864      // N_SHOTS*N_SAMPLES == NPIX*NPIX
#define NPIX 192
#define SPLITS 128
#define MPS (MTOT / SPLITS)     // 288 m per split
#define ADJ_CHUNKS (MPS / 16)   // 18 chunks of 16 m (32 K) per split
#define PG 4                    // partial output images

typedef __attribute__((ext_vector_type(8))) short s16x8;
typedef __attribute__((ext_vector_type(4))) float f32x4;
typedef __attribute__((ext_vector_type(4))) unsigned u32x4;

__device__ __forceinline__ f32x4 mfma_bf16(u32x4 a, u32x4 b, f32x4 c) {
    return __builtin_amdgcn_mfma_f32_16x16x32_bf16(
        __builtin_bit_cast(s16x8, a), __builtin_bit_cast(s16x8, b), c, 0, 0, 0);
}

// Split (a,b) into packed bf16 pairs: hi = (bf16(a) | bf16(b)<<16), lo = residuals.
__device__ __forceinline__ void split_pk(float a, float b, unsigned &hi, unsigned &lo) {
    const unsigned ua = __float_as_uint(a), ub = __float_as_uint(b);
    const unsigned ha = (ua + 0x8000u) & 0xffff0000u;
    const unsigned hb = (ub + 0x8000u) & 0xffff0000u;
    hi = (ha >> 16) | hb;
    const float la = a - __uint_as_float(ha);
    const float lb = b - __uint_as_float(hb);
    lo = ((__float_as_uint(la) + 0x8000u) >> 16) |
         ((__float_as_uint(lb) + 0x8000u) & 0xffff0000u);
}

// k split into 12-bit hi + residual so kh*p (p integer, |p|<=96) is EXACT in fp32.
__device__ __forceinline__ void ksplit(float k, float &kh, float &kl) {
    kh = __uint_as_float(__float_as_uint(k) & 0xfffff000u);
    kl = k - kh;
}
__device__ __forceinline__ float redphase(float kh, float kl, float p) {
    float r = kh * p;
    r -= rintf(r);
    r = fmaf(kl, p, r);
    return r;                   // revolutions, |r| <= ~0.512
}
__device__ __forceinline__ unsigned rot16(unsigned v) {
    return __builtin_amdgcn_alignbit(v, v, 16);
}

// ---------------------------------------------------------------------------
// Precompute packed B phasor (cos, -sin) hi/lo, CHUNK-CONTIGUOUS layout
// (r9-verified): PS[mc][plane][c(192)][mi(16)].
__global__ void precompP_k(const float* __restrict__ traj, const int comp,
                           unsigned* __restrict__ PS) {
    const int m = blockIdx.x * 256 + threadIdx.x;
    const int c = blockIdx.y;
    float kh, kl; ksplit(traj[2 * m + comp], kh, kl);
    const float ph = redphase(kh, kl, (float)(c - 96));
    const float co = __builtin_amdgcn_cosf(ph);
    const float si = __builtin_amdgcn_sinf(ph);
    unsigned h, l; split_pk(co, -si, h, l);
    const int mc = m >> 4, mi = m & 15;
    PS[(size_t)mc * 6144 + c * 16 + mi]        = h;
    PS[(size_t)mc * 6144 + 3072 + c * 16 + mi] = l;
}

// E[m,x] = conj(A[m,x]) * d[m], packed bf16 hi/lo, same chunk layout.
__global__ void ebuild_k(const float* __restrict__ traj,
                         const float* __restrict__ dr, const float* __restrict__ di,
                         unsigned* __restrict__ ES) {
    const int m = blockIdx.x * 256 + threadIdx.x;
    const int c = blockIdx.y;                        // x coordinate
    float kh, kl; ksplit(traj[2 * m], kh, kl);
    const float ph = redphase(kh, kl, (float)(c - 96));
    const float co = __builtin_amdgcn_cosf(ph);
    const float si = __builtin_amdgcn_sinf(ph);
    const float dr_ = dr[m], di_ = di[m];
    const float Er = co * dr_ - si * di_;
    const float Ei = co * di_ + si * dr_;
    unsigned h, l; split_pk(Er, Ei, h, l);
    const int mc = m >> 4, mi = m & 15;
    ES[(size_t)mc * 6144 + c * 16 + mi]        = h;
    ES[(size_t)mc * 6144 + 3072 + c * 16 + mi] = l;
}

__global__ void winit_k(float* __restrict__ wr, float* __restrict__ wi) {
    const int m = blockIdx.x * 256 + threadIdx.x;
    wr[m] = 1.f; wi[m] = 0.f;
}

// ---------------------------------------------------------------------------
// Adjoint pure GEMM: out[x,y] += sum_m E[m,x]*conj(B[m,y]).
// Wave tile 32x32 (2x2 subtiles, 32 acc AGPRs); block = 4 waves = 64x64;
// grid (9 tiles, 128 splits). Direct coalesced u32x4 frag loads, no LDS.
__global__ __launch_bounds__(256) void adj_gemm_k(
    const unsigned* __restrict__ ES, const unsigned* __restrict__ BS,
    float* __restrict__ outP)
{
    const int tid = threadIdx.x;
    const int lane = tid & 63, wid = tid >> 6;     // wid 0..3
    const int l15 = lane & 15, qd = lane >> 4;
    const int bx = blockIdx.x % 3, by = blockIdx.x / 3;
    const int wi = wid & 1, wj = wid >> 1;
    const int x0 = bx * 64 + wi * 32, y0 = by * 64 + wj * 32;
    const int s = blockIdx.y;                      // split 0..127
    float* outRe = outP + (size_t)(s & (PG - 1)) * (2 * MTOT);
    float* outIm = outRe + MTOT;

    f32x4 accRe[2][2], accIm[2][2];
    #pragma unroll
    for (int i = 0; i < 2; ++i)
        #pragma unroll
        for (int j = 0; j < 2; ++j) {
            accRe[i][j] = (f32x4){0.f, 0.f, 0.f, 0.f};
            accIm[i][j] = (f32x4){0.f, 0.f, 0.f, 0.f};
        }

    int aoff[2], boff[2];                          // fragment offsets (r9-verified form)
    #pragma unroll
    for (int t = 0; t < 2; ++t) {
        aoff[t] = (x0 + t * 16 + l15) * 16 + qd * 4;
        boff[t] = (y0 + t * 16 + l15) * 16 + qd * 4;
    }
    const unsigned* Eb = ES + (size_t)(s * ADJ_CHUNKS) * 6144;
    const unsigned* Bb = BS + (size_t)(s * ADJ_CHUNKS) * 6144;

    for (int ch = 0; ch < ADJ_CHUNKS; ++ch) {
        const unsigned* Ec = Eb + (size_t)ch * 6144;
        const unsigned* Bc = Bb + (size_t)ch * 6144;
        u32x4 Eh[2], El[2];
        #pragma unroll
        for (int t = 0; t < 2; ++t) {
            Eh[t] = *(const u32x4*)(Ec + aoff[t]);
            El[t] = *(const u32x4*)(Ec + 3072 + aoff[t]);
        }
        #pragma unroll
        for (int sj = 0; sj < 2; ++sj) {
            const u32x4 Ph = *(const u32x4*)(Bc + boff[sj]);          // (cb, -sb)
            const u32x4 Pl = *(const u32x4*)(Bc + 3072 + boff[sj]);
            u32x4 Qh, Ql;
            #pragma unroll
            for (int r = 0; r < 4; ++r) {
                Qh[r] = rot16(Ph[r]) ^ 0x00008000u;                   // (sb, cb)
                Ql[r] = rot16(Pl[r]) ^ 0x00008000u;
            }
            #pragma unroll
            for (int si = 0; si < 2; ++si) {
                accRe[si][sj] = mfma_bf16(Eh[si], Ph, accRe[si][sj]);
                accRe[si][sj] = mfma_bf16(Eh[si], Pl, accRe[si][sj]);
                accRe[si][sj] = mfma_bf16(El[si], Ph, accRe[si][sj]);
                accIm[si][sj] = mfma_bf16(Eh[si], Qh, accIm[si][sj]);
                accIm[si][sj] = mfma_bf16(Eh[si], Ql, accIm[si][sj]);
                accIm[si][sj] = mfma_bf16(El[si], Qh, accIm[si][sj]);
            }
        }
    }

    // epilogue: direct global atomics into partial image (r8-verified mapping)
    #pragma unroll
    for (int si = 0; si < 2; ++si)
        #pragma unroll
        for (int sj = 0; sj < 2; ++sj)
            #pragma unroll
            for (int rg = 0; rg < 4; ++rg) {
                const int x = x0 + si * 16 + qd * 4 + rg;   // C/D row
                const int y = y0 + sj * 16 + l15;           // C/D col
                atomicAdd(outRe + x * NPIX + y, accRe[si][sj][rg]);
                atomicAdd(outIm + x * NPIX + y, accIm[si][sj][rg]);
            }
}

// ---------------------------------------------------------------------------
// fwdq: q[m] = sum_x A[m,x] * (sum_y B[m,y]*g[x,y]).   (unchanged from r5)
__device__ __forceinline__ void fw_stage_load(const unsigned* __restrict__ Ghi,
                                              const unsigned* __restrict__ Glo,
                                              int tid, int koff, u32x4 st[3]) {
    #pragma unroll
    for (int j = 0; j < 3; ++j) {
        const int li = tid + j * 576;
        if (li < 1536) {
            const int row = li >> 3, pl = (li >> 2) & 1, qt = li & 3;
            const unsigned* src = pl ? Glo : Ghi;
            st[j] = *(const u32x4*)(src + row * 192 + koff + qt * 4);
        }
    }
}
__device__ __forceinline__ void fw_stage_write(unsigned* sb, int tid, const u32x4 st[3]) {
    #pragma unroll
    for (int j = 0; j < 3; ++j) {
        const int li = tid + j * 576;
        if (li < 1536) {
            const int row = li >> 3, pl = (li >> 2) & 1, qt = li & 3;
            *(u32x4*)(sb + pl * 3840 + row * 20 + qt * 4) = st[j];
        }
    }
}

__global__ __launch_bounds__(576) void fwdq_k(
    const float* __restrict__ traj,
    const unsigned* __restrict__ Ghi, const unsigned* __restrict__ Glo,
    float* __restrict__ wre, float* __restrict__ wim,
    const int mode,
    float* __restrict__ qre, float* __restrict__ qim)
{
    __shared__ unsigned sG[2][2 * 3840];   // 60 KB
    const int tid = threadIdx.x;
    const int lane = tid & 63, wid = tid >> 6;         // wid 0..8
    const int l15 = lane & 15, q = lane >> 4;
    const int m = (blockIdx.x * 9 + wid) * 16 + l15;
    const float2 kk = *(const float2*)(traj + 2 * m);
    float kxh, kxl, kyh, kyl;
    ksplit(kk.x, kxh, kxl);
    ksplit(kk.y, kyh, kyl);

    f32x4 tre[12], tim[12];
    #pragma unroll
    for (int i = 0; i < 12; ++i) {
        tre[i] = (f32x4){0.f, 0.f, 0.f, 0.f};
        tim[i] = (f32x4){0.f, 0.f, 0.f, 0.f};
    }

    float bc, bs;
    { const float ph = redphase(kyh, kyl, (float)(q * 4 - 96)); 
      bc = __builtin_amdgcn_cosf(ph); bs = __builtin_amdgcn_sinf(ph); }
    const float r1c = __builtin_amdgcn_cosf(kk.y), r1s = __builtin_amdgcn_sinf(kk.y);
    float r16c, r16s;
    { float g = kk.y * 16.f; g -= rintf(g);
      r16c = __builtin_amdgcn_cosf(g); r16s = __builtin_amdgcn_sinf(g); }

    u32x4 st[3];
    fw_stage_load(Ghi, Glo, tid, 0, st);
    fw_stage_write(&sG[0][0], tid, st);
    __syncthreads();

    for (int ch = 0; ch < 12; ++ch) {
        if (ch < 11) fw_stage_load(Ghi, Glo, tid, (ch + 1) * 16, st);

        u32x4 Ph, Pl, Qh, Ql;
        {
            float c = bc, s = bs;
            #pragma unroll
            for (int r = 0; r < 4; ++r) {
                unsigned h, l; split_pk(c, s, h, l);
                Ph[r] = h; Pl[r] = l;
                Qh[r] = rot16(h) ^ 0x00008000u;
                Ql[r] = rot16(l) ^ 0x00008000u;
                const float nc = c * r1c - s * r1s, ns = s * r1c + c * r1s;
                c = nc; s = ns;
            }
            const float nbc = bc * r16c - bs * r16s, nbs = bs * r16c + bc * r16s;
            bc = nbc; bs = nbs;
        }

        const unsigned* sb = &sG[ch & 1][0];
        #pragma unroll
        for (int si = 0; si < 12; ++si) {
            const int base = (si * 16 + l15) * 20 + q * 4;
            const u32x4 gh = *(const u32x4*)(sb + base);
            const u32x4 gl = *(const u32x4*)(sb + 3840 + base);
            tre[si] = mfma_bf16(gh, Ph, tre[si]);
            tre[si] = mfma_bf16(gh, Pl, tre[si]);
            tre[si] = mfma_bf16(gl, Ph, tre[si]);
            tim[si] = mfma_bf16(gh, Qh, tim[si]);
            tim[si] = mfma_bf16(gh, Ql, tim[si]);
            tim[si] = mfma_bf16(gl, Qh, tim[si]);
        }

        if (ch < 11) {
            __syncthreads();
            fw_stage_write(&sG[(ch + 1) & 1][0], tid, st);
            __syncthreads();
        }
    }

    float qr = 0.f, qi = 0.f;
    {
        float g = kk.x * 16.f; g -= rintf(g);
        const float rc = __builtin_amdgcn_cosf(g), rs = __builtin_amdgcn_sinf(g);
        #pragma unroll
        for (int rg = 0; rg < 4; ++rg) {
            const float ph = redphase(kxh, kxl, (float)(q * 4 + rg - 96));
            float c = __builtin_amdgcn_cosf(ph), s = __builtin_amdgcn_sinf(ph);
            #pragma unroll
            for (int si = 0; si < 12; ++si) {
                const float tr = tre[si][rg], ti = tim[si][rg];
                qr += c * tr + s * ti;
                qi += c * ti - s * tr;
                const float nc = c * rc - s * rs, ns = s * rc + c * rs;
                c = nc; s = ns;
            }
        }
    }
    qr += __shfl_xor(qr, 16); qi += __shfl_xor(qi, 16);
    qr += __shfl_xor(qr, 32); qi += __shfl_xor(qi, 32);
    if (lane < 16) {
        if (mode == 0) {
            const float den = fmaxf(sqrtf(qr * qr + qi * qi), 1e-20f);
            wre[m] /= den; wim[m] /= den;
        } else {
            const float sc = sqrtf(wre[m] * wre[m] + wim[m] * wim[m]);
            qre[m] = qr * sc; qim[m] = qi * sc;
        }
    }
}

// ---------------------------------------------------------------------------
__global__ void presplit_k(const float* __restrict__ re, const float* __restrict__ im,
                           unsigned* __restrict__ Gh, unsigned* __restrict__ Gl) {
    const int e = blockIdx.x * 256 + threadIdx.x;
    unsigned h, l;
    split_pk(re[e], im[e], h, l);     // low16 = re (even K), high16 = im (odd K)
    Gh[e] = h; Gl[e] = l;
}

// Reduce PG partial images + presplit (pipe path)
__global__ void presplitP_k(const float* __restrict__ outP,
                            unsigned* __restrict__ Gh, unsigned* __restrict__ Gl) {
    const int e = blockIdx.x * 256 + threadIdx.x;
    float re = 0.f, im = 0.f;
    #pragma unroll
    for (int g = 0; g < PG; ++g) {
        re += outP[(size_t)g * (2 * MTOT) + e];
        im += outP[(size_t)g * (2 * MTOT) + MTOT + e];
    }
    unsigned h, l;
    split_pk(re, im, h, l);
    Gh[e] = h; Gl[e] = l;
}

// Reduce PG partial images -> final output
__global__ void reduceOut_k(const float* __restrict__ outP, float* __restrict__ out) {
    const int e = blockIdx.x * 256 + threadIdx.x;
    float re = 0.f, im = 0.f;
    #pragma unroll
    for (int g = 0; g < PG; ++g) {
        re += outP[(size_t)g * (2 * MTOT) + e];
        im += outP[(size_t)g * (2 * MTOT) + MTOT + e];
    }
    out[e] = re; out[MTOT + e] = im;
}

// ---------------------------------------------------------------------------
extern "C" void kernel_launch(void* const* d_in, const int* in_sizes, int n_in,
                              void* d_out, int out_size, void* d_ws, size_t ws_size,
                              hipStream_t stream)
{
    const float* xin  = (const float*)d_in[0];   // (2,192,192)
    const float* traj = (const float*)d_in[1];   // (36864,2)
    float* out = (float*)d_out;                  // (2,192,192)

    char* pb = (char*)d_ws;
    unsigned* BS = (unsigned*)pb; pb += (size_t)2304 * 6144 * 4;   // 56.6 MB
    unsigned* ES = (unsigned*)pb; pb += (size_t)2304 * 6144 * 4;   // 56.6 MB
    float* outP = (float*)pb; pb += (size_t)PG * 2 * MTOT * 4;
    float* wr   = (float*)pb; pb += MTOT * 4;
    float* wi   = (float*)pb; pb += MTOT * 4;
    float* dre  = (float*)pb; pb += MTOT * 4;
    float* dim_ = (float*)pb; pb += MTOT * 4;
    unsigned* Ghi = (unsigned*)pb; pb += MTOT * 4;
    unsigned* Glo = (unsigned*)pb; pb += MTOT * 4;

    precompP_k<<<dim3(MTOT / 256, NPIX), 256, 0, stream>>>(traj, 1, BS);
    winit_k<<<MTOT / 256, 256, 0, stream>>>(wr, wi);

    for (int it = 0; it < 3; ++it) {
        hipMemsetAsync(outP, 0, (size_t)PG * 2 * MTOT * 4, stream);
        ebuild_k<<<dim3(MTOT / 256, NPIX), 256, 0, stream>>>(traj, wr, wi, ES);
        adj_gemm_k<<<dim3(9, SPLITS), 256, 0, stream>>>(ES, BS, outP);
        presplitP_k<<<MTOT / 256, 256, 0, stream>>>(outP, Ghi, Glo);
        fwdq_k<<<256, 576, 0, stream>>>(traj, Ghi, Glo, wr, wi, 0, dre, dim_);
    }

    presplit_k<<<MTOT / 256, 256, 0, stream>>>(xin, xin + MTOT, Ghi, Glo);
    fwdq_k<<<256, 576, 0, stream>>>(traj, Ghi, Glo, wr, wi, 1, dre, dim_);
    hipMemsetAsync(outP, 0, (size_t)PG * 2 * MTOT * 4, stream);
    ebuild_k<<<dim3(MTOT / 256, NPIX), 256, 0, stream>>>(traj, dre, dim_, ES);
    adj_gemm_k<<<dim3(9, SPLITS), 256, 0, stream>>>(ES, BS, outP);
    reduceOut_k<<<MTOT / 256, 256, 0, stream>>>(outP, out);
}

// Round 13
// 592.705 us; speedup vs baseline: 1.0741x; 1.0225x over previous
//
#include <hip/hip_runtime.h>
#include <math.h>

// Radial NUFFT + Pipe-Menon density compensation, MI355X (gfx950).
// bf16 MFMA (16x16x32), 2-term hi/lo split (3 products). Round 13 = round 12
// + two adj-only changes: (1) XCD-swizzled block mapping so one split's 9
// tiles co-run on one XCD (L2-shares the chunk stream); (2) register
// double-buffer prefetch of the 8 fragment loads per chunk.

#define MTOT 36864      // N_SHOTS*N_SAMPLES == NPIX*NPIX
#define NPIX 192
#define SPLITS 128
#define MPS (MTOT / SPLITS)     // 288 m per split
#define ADJ_CHUNKS (MPS / 16)   // 18 chunks of 16 m (32 K) per split
#define PG 4                    // partial output images

typedef __attribute__((ext_vector_type(8))) short s16x8;
typedef __attribute__((ext_vector_type(4))) float f32x4;
typedef __attribute__((ext_vector_type(4))) unsigned u32x4;

__device__ __forceinline__ f32x4 mfma_bf16(u32x4 a, u32x4 b, f32x4 c) {
    return __builtin_amdgcn_mfma_f32_16x16x32_bf16(
        __builtin_bit_cast(s16x8, a), __builtin_bit_cast(s16x8, b), c, 0, 0, 0);
}

// Split (a,b) into packed bf16 pairs: hi = (bf16(a) | bf16(b)<<16), lo = residuals.
__device__ __forceinline__ void split_pk(float a, float b, unsigned &hi, unsigned &lo) {
    const unsigned ua = __float_as_uint(a), ub = __float_as_uint(b);
    const unsigned ha = (ua + 0x8000u) & 0xffff0000u;
    const unsigned hb = (ub + 0x8000u) & 0xffff0000u;
    hi = (ha >> 16) | hb;
    const float la = a - __uint_as_float(ha);
    const float lb = b - __uint_as_float(hb);
    lo = ((__float_as_uint(la) + 0x8000u) >> 16) |
         ((__float_as_uint(lb) + 0x8000u) & 0xffff0000u);
}

// k split into 12-bit hi + residual so kh*p (p integer, |p|<=96) is EXACT in fp32.
__device__ __forceinline__ void ksplit(float k, float &kh, float &kl) {
    kh = __uint_as_float(__float_as_uint(k) & 0xfffff000u);
    kl = k - kh;
}
__device__ __forceinline__ float redphase(float kh, float kl, float p) {
    float r = kh * p;
    r -= rintf(r);
    r = fmaf(kl, p, r);
    return r;                   // revolutions, |r| <= ~0.512
}
__device__ __forceinline__ unsigned rot16(unsigned v) {
    return __builtin_amdgcn_alignbit(v, v, 16);
}

// ---------------------------------------------------------------------------
// Precompute packed B phasor (cos, -sin) hi/lo, CHUNK-CONTIGUOUS layout
// (r9-verified): PS[mc][plane][c(192)][mi(16)].
__global__ void precompP_k(const float* __restrict__ traj, const int comp,
                           unsigned* __restrict__ PS) {
    const int m = blockIdx.x * 256 + threadIdx.x;
    const int c = blockIdx.y;
    float kh, kl; ksplit(traj[2 * m + comp], kh, kl);
    const float ph = redphase(kh, kl, (float)(c - 96));
    const float co = __builtin_amdgcn_cosf(ph);
    const float si = __builtin_amdgcn_sinf(ph);
    unsigned h, l; split_pk(co, -si, h, l);
    const int mc = m >> 4, mi = m & 15;
    PS[(size_t)mc * 6144 + c * 16 + mi]        = h;
    PS[(size_t)mc * 6144 + 3072 + c * 16 + mi] = l;
}

// E[m,x] = conj(A[m,x]) * d[m], packed bf16 hi/lo, same chunk layout.
__global__ void ebuild_k(const float* __restrict__ traj,
                         const float* __restrict__ dr, const float* __restrict__ di,
                         unsigned* __restrict__ ES) {
    const int m = blockIdx.x * 256 + threadIdx.x;
    const int c = blockIdx.y;                        // x coordinate
    float kh, kl; ksplit(traj[2 * m], kh, kl);
    const float ph = redphase(kh, kl, (float)(c - 96));
    const float co = __builtin_amdgcn_cosf(ph);
    const float si = __builtin_amdgcn_sinf(ph);
    const float dr_ = dr[m], di_ = di[m];
    const float Er = co * dr_ - si * di_;
    const float Ei = co * di_ + si * dr_;
    unsigned h, l; split_pk(Er, Ei, h, l);
    const int mc = m >> 4, mi = m & 15;
    ES[(size_t)mc * 6144 + c * 16 + mi]        = h;
    ES[(size_t)mc * 6144 + 3072 + c * 16 + mi] = l;
}

__global__ void winit_k(float* __restrict__ wr, float* __restrict__ wi) {
    const int m = blockIdx.x * 256 + threadIdx.x;
    wr[m] = 1.f; wi[m] = 0.f;
}

// ---------------------------------------------------------------------------
// Adjoint pure GEMM: out[x,y] += sum_m E[m,x]*conj(B[m,y]).
// Wave tile 32x32; block = 4 waves = 64x64; 1152 blocks, XCD-swizzled so
// each split's 9 tiles co-run on one XCD (split stream L2-resident).
// Fragment loads register-double-buffered (prefetch chunk ch+1 before
// computing chunk ch). Epilogue: PG=4 partial-image atomics.
__global__ __launch_bounds__(256) void adj_gemm_k(
    const unsigned* __restrict__ ES, const unsigned* __restrict__ BS,
    float* __restrict__ outP)
{
    const int tid = threadIdx.x;
    const int lane = tid & 63, wid = tid >> 6;     // wid 0..3
    const int l15 = lane & 15, qd = lane >> 4;
    // XCD swizzle: consecutive blockIdx round-robin across 8 XCDs; pick
    // (split, tile) so that one split's 9 tiles share an XCD.
    const int L = blockIdx.x;                      // 0..1151
    const int xcd = L & 7, j = L >> 3;             // j 0..143
    const int s = xcd * (SPLITS / 8) + j / 9;      // split 0..127
    const int tile = j % 9;
    const int bx = tile % 3, by = tile / 3;
    const int wi = wid & 1, wj = wid >> 1;
    const int x0 = bx * 64 + wi * 32, y0 = by * 64 + wj * 32;
    float* outRe = outP + (size_t)(s & (PG - 1)) * (2 * MTOT);
    float* outIm = outRe + MTOT;

    f32x4 accRe[2][2], accIm[2][2];
    #pragma unroll
    for (int i = 0; i < 2; ++i)
        #pragma unroll
        for (int j2 = 0; j2 < 2; ++j2) {
            accRe[i][j2] = (f32x4){0.f, 0.f, 0.f, 0.f};
            accIm[i][j2] = (f32x4){0.f, 0.f, 0.f, 0.f};
        }

    int aoff[2], boff[2];                          // fragment offsets (r9-verified form)
    #pragma unroll
    for (int t = 0; t < 2; ++t) {
        aoff[t] = (x0 + t * 16 + l15) * 16 + qd * 4;
        boff[t] = (y0 + t * 16 + l15) * 16 + qd * 4;
    }
    const unsigned* Eb = ES + (size_t)(s * ADJ_CHUNKS) * 6144;
    const unsigned* Bb = BS + (size_t)(s * ADJ_CHUNKS) * 6144;

    u32x4 Eh[2][2], El[2][2], Bh[2][2], Bl[2][2];  // [buf][t]
    #pragma unroll
    for (int t = 0; t < 2; ++t) {                  // load chunk 0 -> buf 0
        Eh[0][t] = *(const u32x4*)(Eb + aoff[t]);
        El[0][t] = *(const u32x4*)(Eb + 3072 + aoff[t]);
        Bh[0][t] = *(const u32x4*)(Bb + boff[t]);
        Bl[0][t] = *(const u32x4*)(Bb + 3072 + boff[t]);
    }

    for (int ch = 0; ch < ADJ_CHUNKS; ++ch) {
        const int cur = ch & 1, nxt = cur ^ 1;
        if (ch + 1 < ADJ_CHUNKS) {                 // prefetch chunk ch+1
            const unsigned* En = Eb + (size_t)(ch + 1) * 6144;
            const unsigned* Bn = Bb + (size_t)(ch + 1) * 6144;
            #pragma unroll
            for (int t = 0; t < 2; ++t) {
                Eh[nxt][t] = *(const u32x4*)(En + aoff[t]);
                El[nxt][t] = *(const u32x4*)(En + 3072 + aoff[t]);
                Bh[nxt][t] = *(const u32x4*)(Bn + boff[t]);
                Bl[nxt][t] = *(const u32x4*)(Bn + 3072 + boff[t]);
            }
        }
        #pragma unroll
        for (int sj = 0; sj < 2; ++sj) {
            const u32x4 Ph = Bh[cur][sj], Pl = Bl[cur][sj];   // (cb, -sb)
            u32x4 Qh, Ql;
            #pragma unroll
            for (int r = 0; r < 4; ++r) {
                Qh[r] = rot16(Ph[r]) ^ 0x00008000u;           // (sb, cb)
                Ql[r] = rot16(Pl[r]) ^ 0x00008000u;
            }
            #pragma unroll
            for (int si = 0; si < 2; ++si) {
                accRe[si][sj] = mfma_bf16(Eh[cur][si], Ph, accRe[si][sj]);
                accRe[si][sj] = mfma_bf16(Eh[cur][si], Pl, accRe[si][sj]);
                accRe[si][sj] = mfma_bf16(El[cur][si], Ph, accRe[si][sj]);
                accIm[si][sj] = mfma_bf16(Eh[cur][si], Qh, accIm[si][sj]);
                accIm[si][sj] = mfma_bf16(Eh[cur][si], Ql, accIm[si][sj]);
                accIm[si][sj] = mfma_bf16(El[cur][si], Qh, accIm[si][sj]);
            }
        }
    }

    // epilogue: direct global atomics into partial image (r8-verified mapping)
    #pragma unroll
    for (int si = 0; si < 2; ++si)
        #pragma unroll
        for (int sj = 0; sj < 2; ++sj)
            #pragma unroll
            for (int rg = 0; rg < 4; ++rg) {
                const int x = x0 + si * 16 + qd * 4 + rg;   // C/D row
                const int y = y0 + sj * 16 + l15;           // C/D col
                atomicAdd(outRe + x * NPIX + y, accRe[si][sj][rg]);
                atomicAdd(outIm + x * NPIX + y, accIm[si][sj][rg]);
            }
}

// ---------------------------------------------------------------------------
// fwdq: q[m] = sum_x A[m,x] * (sum_y B[m,y]*g[x,y]).   (unchanged from r5)
__device__ __forceinline__ void fw_stage_load(const unsigned* __restrict__ Ghi,
                                              const unsigned* __restrict__ Glo,
                                              int tid, int koff, u32x4 st[3]) {
    #pragma unroll
    for (int j = 0; j < 3; ++j) {
        const int li = tid + j * 576;
        if (li < 1536) {
            const int row = li >> 3, pl = (li >> 2) & 1, qt = li & 3;
            const unsigned* src = pl ? Glo : Ghi;
            st[j] = *(const u32x4*)(src + row * 192 + koff + qt * 4);
        }
    }
}
__device__ __forceinline__ void fw_stage_write(unsigned* sb, int tid, const u32x4 st[3]) {
    #pragma unroll
    for (int j = 0; j < 3; ++j) {
        const int li = tid + j * 576;
        if (li < 1536) {
            const int row = li >> 3, pl = (li >> 2) & 1, qt = li & 3;
            *(u32x4*)(sb + pl * 3840 + row * 20 + qt * 4) = st[j];
        }
    }
}

__global__ __launch_bounds__(576) void fwdq_k(
    const float* __restrict__ traj,
    const unsigned* __restrict__ Ghi, const unsigned* __restrict__ Glo,
    float* __restrict__ wre, float* __restrict__ wim,
    const int mode,
    float* __restrict__ qre, float* __restrict__ qim)
{
    __shared__ unsigned sG[2][2 * 3840];   // 60 KB
    const int tid = threadIdx.x;
    const int lane = tid & 63, wid = tid >> 6;         // wid 0..8
    const int l15 = lane & 15, q = lane >> 4;
    const int m = (blockIdx.x * 9 + wid) * 16 + l15;
    const float2 kk = *(const float2*)(traj + 2 * m);
    float kxh, kxl, kyh, kyl;
    ksplit(kk.x, kxh, kxl);
    ksplit(kk.y, kyh, kyl);

    f32x4 tre[12], tim[12];
    #pragma unroll
    for (int i = 0; i < 12; ++i) {
        tre[i] = (f32x4){0.f, 0.f, 0.f, 0.f};
        tim[i] = (f32x4){0.f, 0.f, 0.f, 0.f};
    }

    float bc, bs;
    { const float ph = redphase(kyh, kyl, (float)(q * 4 - 96)); 
      bc = __builtin_amdgcn_cosf(ph); bs = __builtin_amdgcn_sinf(ph); }
    const float r1c = __builtin_amdgcn_cosf(kk.y), r1s = __builtin_amdgcn_sinf(kk.y);
    float r16c, r16s;
    { float g = kk.y * 16.f; g -= rintf(g);
      r16c = __builtin_amdgcn_cosf(g); r16s = __builtin_amdgcn_sinf(g); }

    u32x4 st[3];
    fw_stage_load(Ghi, Glo, tid, 0, st);
    fw_stage_write(&sG[0][0], tid, st);
    __syncthreads();

    for (int ch = 0; ch < 12; ++ch) {
        if (ch < 11) fw_stage_load(Ghi, Glo, tid, (ch + 1) * 16, st);

        u32x4 Ph, Pl, Qh, Ql;
        {
            float c = bc, s = bs;
            #pragma unroll
            for (int r = 0; r < 4; ++r) {
                unsigned h, l; split_pk(c, s, h, l);
                Ph[r] = h; Pl[r] = l;
                Qh[r] = rot16(h) ^ 0x00008000u;
                Ql[r] = rot16(l) ^ 0x00008000u;
                const float nc = c * r1c - s * r1s, ns = s * r1c + c * r1s;
                c = nc; s = ns;
            }
            const float nbc = bc * r16c - bs * r16s, nbs = bs * r16c + bc * r16s;
            bc = nbc; bs = nbs;
        }

        const unsigned* sb = &sG[ch & 1][0];
        #pragma unroll
        for (int si = 0; si < 12; ++si) {
            const int base = (si * 16 + l15) * 20 + q * 4;
            const u32x4 gh = *(const u32x4*)(sb + base);
            const u32x4 gl = *(const u32x4*)(sb + 3840 + base);
            tre[si] = mfma_bf16(gh, Ph, tre[si]);
            tre[si] = mfma_bf16(gh, Pl, tre[si]);
            tre[si] = mfma_bf16(gl, Ph, tre[si]);
            tim[si] = mfma_bf16(gh, Qh, tim[si]);
            tim[si] = mfma_bf16(gh, Ql, tim[si]);
            tim[si] = mfma_bf16(gl, Qh, tim[si]);
        }

        if (ch < 11) {
            __syncthreads();
            fw_stage_write(&sG[(ch + 1) & 1][0], tid, st);
            __syncthreads();
        }
    }

    float qr = 0.f, qi = 0.f;
    {
        float g = kk.x * 16.f; g -= rintf(g);
        const float rc = __builtin_amdgcn_cosf(g), rs = __builtin_amdgcn_sinf(g);
        #pragma unroll
        for (int rg = 0; rg < 4; ++rg) {
            const float ph = redphase(kxh, kxl, (float)(q * 4 + rg - 96));
            float c = __builtin_amdgcn_cosf(ph), s = __builtin_amdgcn_sinf(ph);
            #pragma unroll
            for (int si = 0; si < 12; ++si) {
                const float tr = tre[si][rg], ti = tim[si][rg];
                qr += c * tr + s * ti;
                qi += c * ti - s * tr;
                const float nc = c * rc - s * rs, ns = s * rc + c * rs;
                c = nc; s = ns;
            }
        }
    }
    qr += __shfl_xor(qr, 16); qi += __shfl_xor(qi, 16);
    qr += __shfl_xor(qr, 32); qi += __shfl_xor(qi, 32);
    if (lane < 16) {
        if (mode == 0) {
            const float den = fmaxf(sqrtf(qr * qr + qi * qi), 1e-20f);
            wre[m] /= den; wim[m] /= den;
        } else {
            const float sc = sqrtf(wre[m] * wre[m] + wim[m] * wim[m]);
            qre[m] = qr * sc; qim[m] = qi * sc;
        }
    }
}

// ---------------------------------------------------------------------------
__global__ void presplit_k(const float* __restrict__ re, const float* __restrict__ im,
                           unsigned* __restrict__ Gh, unsigned* __restrict__ Gl) {
    const int e = blockIdx.x * 256 + threadIdx.x;
    unsigned h, l;
    split_pk(re[e], im[e], h, l);     // low16 = re (even K), high16 = im (odd K)
    Gh[e] = h; Gl[e] = l;
}

// Reduce PG partial images + presplit (pipe path)
__global__ void presplitP_k(const float* __restrict__ outP,
                            unsigned* __restrict__ Gh, unsigned* __restrict__ Gl) {
    const int e = blockIdx.x * 256 + threadIdx.x;
    float re = 0.f, im = 0.f;
    #pragma unroll
    for (int g = 0; g < PG; ++g) {
        re += outP[(size_t)g * (2 * MTOT) + e];
        im += outP[(size_t)g * (2 * MTOT) + MTOT + e];
    }
    unsigned h, l;
    split_pk(re, im, h, l);
    Gh[e] = h; Gl[e] = l;
}

// Reduce PG partial images -> final output
__global__ void reduceOut_k(const float* __restrict__ outP, float* __restrict__ out) {
    const int e = blockIdx.x * 256 + threadIdx.x;
    float re = 0.f, im = 0.f;
    #pragma unroll
    for (int g = 0; g < PG; ++g) {
        re += outP[(size_t)g * (2 * MTOT) + e];
        im += outP[(size_t)g * (2 * MTOT) + MTOT + e];
    }
    out[e] = re; out[MTOT + e] = im;
}

// ---------------------------------------------------------------------------
extern "C" void kernel_launch(void* const* d_in, const int* in_sizes, int n_in,
                              void* d_out, int out_size, void* d_ws, size_t ws_size,
                              hipStream_t stream)
{
    const float* xin  = (const float*)d_in[0];   // (2,192,192)
    const float* traj = (const float*)d_in[1];   // (36864,2)
    float* out = (float*)d_out;                  // (2,192,192)

    char* pb = (char*)d_ws;
    unsigned* BS = (unsigned*)pb; pb += (size_t)2304 * 6144 * 4;   // 56.6 MB
    unsigned* ES = (unsigned*)pb; pb += (size_t)2304 * 6144 * 4;   // 56.6 MB
    float* outP = (float*)pb; pb += (size_t)PG * 2 * MTOT * 4;
    float* wr   = (float*)pb; pb += MTOT * 4;
    float* wi   = (float*)pb; pb += MTOT * 4;
    float* dre  = (float*)pb; pb += MTOT * 4;
    float* dim_ = (float*)pb; pb += MTOT * 4;
    unsigned* Ghi = (unsigned*)pb; pb += MTOT * 4;
    unsigned* Glo = (unsigned*)pb; pb += MTOT * 4;

    precompP_k<<<dim3(MTOT / 256, NPIX), 256, 0, stream>>>(traj, 1, BS);
    winit_k<<<MTOT / 256, 256, 0, stream>>>(wr, wi);

    for (int it = 0; it < 3; ++it) {
        hipMemsetAsync(outP, 0, (size_t)PG * 2 * MTOT * 4, stream);
        ebuild_k<<<dim3(MTOT / 256, NPIX), 256, 0, stream>>>(traj, wr, wi, ES);
        adj_gemm_k<<<9 * SPLITS, 256, 0, stream>>>(ES, BS, outP);
        presplitP_k<<<MTOT / 256, 256, 0, stream>>>(outP, Ghi, Glo);
        fwdq_k<<<256, 576, 0, stream>>>(traj, Ghi, Glo, wr, wi, 0, dre, dim_);
    }

    presplit_k<<<MTOT / 256, 256, 0, stream>>>(xin, xin + MTOT, Ghi, Glo);
    fwdq_k<<<256, 576, 0, stream>>>(traj, Ghi, Glo, wr, wi, 1, dre, dim_);
    hipMemsetAsync(outP, 0, (size_t)PG * 2 * MTOT * 4, stream);
    ebuild_k<<<dim3(MTOT / 256, NPIX), 256, 0, stream>>>(traj, dre, dim_, ES);
    adj_gemm_k<<<9 * SPLITS, 256, 0, stream>>>(ES, BS, outP);
    reduceOut_k<<<MTOT / 256, 256, 0, stream>>>(outP, out);
}

// Round 14
// 491.518 us; speedup vs baseline: 1.2953x; 1.2059x over previous
//
#include <hip/hip_runtime.h>
#include <math.h>

// Radial NUFFT + Pipe-Menon density compensation, MI355X (gfx950).
// bf16 MFMA (16x16x32), 2-term hi/lo split (3 products). Round 14 = round 13
// (pure-GEMM adj, E-table, XCD swizzle) + un-deletable prefetch: each chunk's
// E/B fragments staged via async global_load_lds (16B) into 32 KB double-
// buffered LDS, ONE barrier per chunk (r10-verified pattern); bank-swizzled
// global layout for conflict-free ds_read_b128 (r10-verified).

#define MTOT 36864      // N_SHOTS*N_SAMPLES == NPIX*NPIX
#define NPIX 192
#define SPLITS 128
#define MPS (MTOT / SPLITS)     // 288 m per split
#define ADJ_CHUNKS (MPS / 16)   // 18 chunks of 16 m (32 K) per split
#define PG 4                    // partial output images

typedef __attribute__((ext_vector_type(8))) short s16x8;
typedef __attribute__((ext_vector_type(4))) float f32x4;
typedef __attribute__((ext_vector_type(4))) unsigned u32x4;

__device__ __forceinline__ f32x4 mfma_bf16(u32x4 a, u32x4 b, f32x4 c) {
    return __builtin_amdgcn_mfma_f32_16x16x32_bf16(
        __builtin_bit_cast(s16x8, a), __builtin_bit_cast(s16x8, b), c, 0, 0, 0);
}

// async 16B/lane global->LDS (DMA, no VGPR roundtrip); wave-uniform base +
// lane*16 LDS dest semantics (our layout matches: tid*16B contiguous).
__device__ __forceinline__ void g2l16(const void* g, void* l) {
    __builtin_amdgcn_global_load_lds(
        (const __attribute__((address_space(1))) void*)g,
        (__attribute__((address_space(3))) void*)l, 16, 0, 0);
}

// Split (a,b) into packed bf16 pairs: hi = (bf16(a) | bf16(b)<<16), lo = residuals.
__device__ __forceinline__ void split_pk(float a, float b, unsigned &hi, unsigned &lo) {
    const unsigned ua = __float_as_uint(a), ub = __float_as_uint(b);
    const unsigned ha = (ua + 0x8000u) & 0xffff0000u;
    const unsigned hb = (ub + 0x8000u) & 0xffff0000u;
    hi = (ha >> 16) | hb;
    const float la = a - __uint_as_float(ha);
    const float lb = b - __uint_as_float(hb);
    lo = ((__float_as_uint(la) + 0x8000u) >> 16) |
         ((__float_as_uint(lb) + 0x8000u) & 0xffff0000u);
}

// k split into 12-bit hi + residual so kh*p (p integer, |p|<=96) is EXACT in fp32.
__device__ __forceinline__ void ksplit(float k, float &kh, float &kl) {
    kh = __uint_as_float(__float_as_uint(k) & 0xfffff000u);
    kl = k - kh;
}
__device__ __forceinline__ float redphase(float kh, float kl, float p) {
    float r = kh * p;
    r -= rintf(r);
    r = fmaf(kl, p, r);
    return r;                   // revolutions, |r| <= ~0.512
}
__device__ __forceinline__ unsigned rot16(unsigned v) {
    return __builtin_amdgcn_alignbit(v, v, 16);
}
__device__ __forceinline__ int swz(int c) {        // bank swizzle (r10-verified)
    return ((c ^ (c >> 2)) & 3) << 2;
}

// ---------------------------------------------------------------------------
// Precompute packed B phasor (cos, -sin) hi/lo, chunk-contiguous + swizzled:
// PS[mc][plane][c(192)][mi^swz(c)]  (r10-verified layout).
__global__ void precompP_k(const float* __restrict__ traj, const int comp,
                           unsigned* __restrict__ PS) {
    const int m = blockIdx.x * 256 + threadIdx.x;
    const int c = blockIdx.y;
    float kh, kl; ksplit(traj[2 * m + comp], kh, kl);
    const float ph = redphase(kh, kl, (float)(c - 96));
    const float co = __builtin_amdgcn_cosf(ph);
    const float si = __builtin_amdgcn_sinf(ph);
    unsigned h, l; split_pk(co, -si, h, l);
    const int mc = m >> 4, mi = (m & 15) ^ swz(c);
    PS[(size_t)mc * 6144 + c * 16 + mi]        = h;
    PS[(size_t)mc * 6144 + 3072 + c * 16 + mi] = l;
}

// E[m,x] = conj(A[m,x]) * d[m], packed bf16 hi/lo, same swizzled layout.
__global__ void ebuild_k(const float* __restrict__ traj,
                         const float* __restrict__ dr, const float* __restrict__ di,
                         unsigned* __restrict__ ES) {
    const int m = blockIdx.x * 256 + threadIdx.x;
    const int c = blockIdx.y;                        // x coordinate
    float kh, kl; ksplit(traj[2 * m], kh, kl);
    const float ph = redphase(kh, kl, (float)(c - 96));
    const float co = __builtin_amdgcn_cosf(ph);
    const float si = __builtin_amdgcn_sinf(ph);
    const float dr_ = dr[m], di_ = di[m];
    const float Er = co * dr_ - si * di_;
    const float Ei = co * di_ + si * dr_;
    unsigned h, l; split_pk(Er, Ei, h, l);
    const int mc = m >> 4, mi = (m & 15) ^ swz(c);
    ES[(size_t)mc * 6144 + c * 16 + mi]        = h;
    ES[(size_t)mc * 6144 + 3072 + c * 16 + mi] = l;
}

__global__ void winit_k(float* __restrict__ wr, float* __restrict__ wi) {
    const int m = blockIdx.x * 256 + threadIdx.x;
    wr[m] = 1.f; wi[m] = 0.f;
}

// ---------------------------------------------------------------------------
// Adjoint pure GEMM: out[x,y] += sum_m E[m,x]*conj(B[m,y]).
// Block = 4 waves (2x2 of 32x32) = 64x64 tile; 1152 blocks XCD-swizzled
// (one split's 9 tiles share an XCD -> L2-resident stream). Per chunk the
// needed E/B rows (16 KB) staged via 4x global_load_lds into dbuf LDS;
// single barrier per chunk drains the prefetch issued a full compute
// phase earlier. Frag reads: bank-swizzled ds_read_b128.
__global__ __launch_bounds__(256) void adj_gemm_k(
    const unsigned* __restrict__ ES, const unsigned* __restrict__ BS,
    float* __restrict__ outP)
{
    __shared__ unsigned sAB[2][4096];              // 32 KB double buffer
    const int tid = threadIdx.x;
    const int lane = tid & 63, wid = tid >> 6;     // wid 0..3
    const int l15 = lane & 15, qd = lane >> 4;
    const int L = blockIdx.x;                      // 0..1151, XCD swizzle
    const int xcd = L & 7, j = L >> 3;
    const int s = xcd * (SPLITS / 8) + j / 9;      // split 0..127
    const int tile = j % 9;
    const int bx = tile % 3, by = tile / 3;
    const int wi = wid & 1, wj = wid >> 1;
    const int x0 = bx * 64 + wi * 32, y0 = by * 64 + wj * 32;
    float* outRe = outP + (size_t)(s & (PG - 1)) * (2 * MTOT);
    float* outIm = outRe + MTOT;

    f32x4 accRe[2][2], accIm[2][2];
    #pragma unroll
    for (int i = 0; i < 2; ++i)
        #pragma unroll
        for (int j2 = 0; j2 < 2; ++j2) {
            accRe[i][j2] = (f32x4){0.f, 0.f, 0.f, 0.f};
            accIm[i][j2] = (f32x4){0.f, 0.f, 0.f, 0.f};
        }

    // staging sources (advance 6144 words/chunk); LDS dest = 4 sections of
    // 1024 words: [E hi | E lo | B hi | B lo], each covering 64 coords x 16.
    const unsigned* gp[4];
    {
        const unsigned* E0 = ES + (size_t)(s * ADJ_CHUNKS) * 6144;
        const unsigned* B0 = BS + (size_t)(s * ADJ_CHUNKS) * 6144;
        gp[0] = E0 + bx * 1024 + tid * 4;          // E hi rows [bx*64..+64)
        gp[1] = E0 + 3072 + bx * 1024 + tid * 4;   // E lo
        gp[2] = B0 + by * 1024 + tid * 4;          // B hi rows [by*64..+64)
        gp[3] = B0 + 3072 + by * 1024 + tid * 4;   // B lo
    }
    // fragment LDS word offsets within a buffer (local coord; swz(local)==swz(global))
    int eoff[2], boff[2];
    #pragma unroll
    for (int t = 0; t < 2; ++t) {
        const int cE = wi * 32 + t * 16 + l15;     // local x coord 0..63
        eoff[t] = cE * 16 + ((qd ^ ((cE ^ (cE >> 2)) & 3)) << 2);
        const int cB = wj * 32 + t * 16 + l15;     // local y coord 0..63
        boff[t] = 2048 + cB * 16 + ((qd ^ ((cB ^ (cB >> 2)) & 3)) << 2);
    }

    #pragma unroll
    for (int v = 0; v < 4; ++v)                    // stage chunk 0 -> buf 0
        g2l16(gp[v], &sAB[0][v * 1024 + tid * 4]);
    __syncthreads();

    for (int ch = 0; ch < ADJ_CHUNKS; ++ch) {
        const int cur = ch & 1, nxt = cur ^ 1;
        if (ch + 1 < ADJ_CHUNKS) {                 // async prefetch chunk ch+1
            #pragma unroll
            for (int v = 0; v < 4; ++v) {
                gp[v] += 6144;
                g2l16(gp[v], &sAB[nxt][v * 1024 + tid * 4]);
            }
        }

        u32x4 Eh[2], El[2];
        #pragma unroll
        for (int t = 0; t < 2; ++t) {
            Eh[t] = *(const u32x4*)(&sAB[cur][eoff[t]]);
            El[t] = *(const u32x4*)(&sAB[cur][1024 + eoff[t]]);
        }
        #pragma unroll
        for (int sj = 0; sj < 2; ++sj) {
            const u32x4 Ph = *(const u32x4*)(&sAB[cur][boff[sj]]);        // (cb,-sb)
            const u32x4 Pl = *(const u32x4*)(&sAB[cur][1024 + boff[sj]]);
            u32x4 Qh, Ql;
            #pragma unroll
            for (int r = 0; r < 4; ++r) {
                Qh[r] = rot16(Ph[r]) ^ 0x00008000u;                       // (sb, cb)
                Ql[r] = rot16(Pl[r]) ^ 0x00008000u;
            }
            #pragma unroll
            for (int si = 0; si < 2; ++si) {
                accRe[si][sj] = mfma_bf16(Eh[si], Ph, accRe[si][sj]);
                accRe[si][sj] = mfma_bf16(Eh[si], Pl, accRe[si][sj]);
                accRe[si][sj] = mfma_bf16(El[si], Ph, accRe[si][sj]);
                accIm[si][sj] = mfma_bf16(Eh[si], Qh, accIm[si][sj]);
                accIm[si][sj] = mfma_bf16(Eh[si], Ql, accIm[si][sj]);
                accIm[si][sj] = mfma_bf16(El[si], Qh, accIm[si][sj]);
            }
        }
        __syncthreads();   // drains this iteration's staging (issued pre-compute)
    }

    // epilogue: direct global atomics into partial image (r8-verified mapping)
    #pragma unroll
    for (int si = 0; si < 2; ++si)
        #pragma unroll
        for (int sj = 0; sj < 2; ++sj)
            #pragma unroll
            for (int rg = 0; rg < 4; ++rg) {
                const int x = x0 + si * 16 + qd * 4 + rg;   // C/D row
                const int y = y0 + sj * 16 + l15;           // C/D col
                atomicAdd(outRe + x * NPIX + y, accRe[si][sj][rg]);
                atomicAdd(outIm + x * NPIX + y, accIm[si][sj][rg]);
            }
}

// ---------------------------------------------------------------------------
// fwdq: q[m] = sum_x A[m,x] * (sum_y B[m,y]*g[x,y]).   (unchanged from r5)
__device__ __forceinline__ void fw_stage_load(const unsigned* __restrict__ Ghi,
                                              const unsigned* __restrict__ Glo,
                                              int tid, int koff, u32x4 st[3]) {
    #pragma unroll
    for (int j = 0; j < 3; ++j) {
        const int li = tid + j * 576;
        if (li < 1536) {
            const int row = li >> 3, pl = (li >> 2) & 1, qt = li & 3;
            const unsigned* src = pl ? Glo : Ghi;
            st[j] = *(const u32x4*)(src + row * 192 + koff + qt * 4);
        }
    }
}
__device__ __forceinline__ void fw_stage_write(unsigned* sb, int tid, const u32x4 st[3]) {
    #pragma unroll
    for (int j = 0; j < 3; ++j) {
        const int li = tid + j * 576;
        if (li < 1536) {
            const int row = li >> 3, pl = (li >> 2) & 1, qt = li & 3;
            *(u32x4*)(sb + pl * 3840 + row * 20 + qt * 4) = st[j];
        }
    }
}

__global__ __launch_bounds__(576) void fwdq_k(
    const float* __restrict__ traj,
    const unsigned* __restrict__ Ghi, const unsigned* __restrict__ Glo,
    float* __restrict__ wre, float* __restrict__ wim,
    const int mode,
    float* __restrict__ qre, float* __restrict__ qim)
{
    __shared__ unsigned sG[2][2 * 3840];   // 60 KB
    const int tid = threadIdx.x;
    const int lane = tid & 63, wid = tid >> 6;         // wid 0..8
    const int l15 = lane & 15, q = lane >> 4;
    const int m = (blockIdx.x * 9 + wid) * 16 + l15;
    const float2 kk = *(const float2*)(traj + 2 * m);
    float kxh, kxl, kyh, kyl;
    ksplit(kk.x, kxh, kxl);
    ksplit(kk.y, kyh, kyl);

    f32x4 tre[12], tim[12];
    #pragma unroll
    for (int i = 0; i < 12; ++i) {
        tre[i] = (f32x4){0.f, 0.f, 0.f, 0.f};
        tim[i] = (f32x4){0.f, 0.f, 0.f, 0.f};
    }

    float bc, bs;
    { const float ph = redphase(kyh, kyl, (float)(q * 4 - 96)); 
      bc = __builtin_amdgcn_cosf(ph); bs = __builtin_amdgcn_sinf(ph); }
    const float r1c = __builtin_amdgcn_cosf(kk.y), r1s = __builtin_amdgcn_sinf(kk.y);
    float r16c, r16s;
    { float g = kk.y * 16.f; g -= rintf(g);
      r16c = __builtin_amdgcn_cosf(g); r16s = __builtin_amdgcn_sinf(g); }

    u32x4 st[3];
    fw_stage_load(Ghi, Glo, tid, 0, st);
    fw_stage_write(&sG[0][0], tid, st);
    __syncthreads();

    for (int ch = 0; ch < 12; ++ch) {
        if (ch < 11) fw_stage_load(Ghi, Glo, tid, (ch + 1) * 16, st);

        u32x4 Ph, Pl, Qh, Ql;
        {
            float c = bc, s = bs;
            #pragma unroll
            for (int r = 0; r < 4; ++r) {
                unsigned h, l; split_pk(c, s, h, l);
                Ph[r] = h; Pl[r] = l;
                Qh[r] = rot16(h) ^ 0x00008000u;
                Ql[r] = rot16(l) ^ 0x00008000u;
                const float nc = c * r1c - s * r1s, ns = s * r1c + c * r1s;
                c = nc; s = ns;
            }
            const float nbc = bc * r16c - bs * r16s, nbs = bs * r16c + bc * r16s;
            bc = nbc; bs = nbs;
        }

        const unsigned* sb = &sG[ch & 1][0];
        #pragma unroll
        for (int si = 0; si < 12; ++si) {
            const int base = (si * 16 + l15) * 20 + q * 4;
            const u32x4 gh = *(const u32x4*)(sb + base);
            const u32x4 gl = *(const u32x4*)(sb + 3840 + base);
            tre[si] = mfma_bf16(gh, Ph, tre[si]);
            tre[si] = mfma_bf16(gh, Pl, tre[si]);
            tre[si] = mfma_bf16(gl, Ph, tre[si]);
            tim[si] = mfma_bf16(gh, Qh, tim[si]);
            tim[si] = mfma_bf16(gh, Ql, tim[si]);
            tim[si] = mfma_bf16(gl, Qh, tim[si]);
        }

        if (ch < 11) {
            __syncthreads();
            fw_stage_write(&sG[(ch + 1) & 1][0], tid, st);
            __syncthreads();
        }
    }

    float qr = 0.f, qi = 0.f;
    {
        float g = kk.x * 16.f; g -= rintf(g);
        const float rc = __builtin_amdgcn_cosf(g), rs = __builtin_amdgcn_sinf(g);
        #pragma unroll
        for (int rg = 0; rg < 4; ++rg) {
            const float ph = redphase(kxh, kxl, (float)(q * 4 + rg - 96));
            float c = __builtin_amdgcn_cosf(ph), s = __builtin_amdgcn_sinf(ph);
            #pragma unroll
            for (int si = 0; si < 12; ++si) {
                const float tr = tre[si][rg], ti = tim[si][rg];
                qr += c * tr + s * ti;
                qi += c * ti - s * tr;
                const float nc = c * rc - s * rs, ns = s * rc + c * rs;
                c = nc; s = ns;
            }
        }
    }
    qr += __shfl_xor(qr, 16); qi += __shfl_xor(qi, 16);
    qr += __shfl_xor(qr, 32); qi += __shfl_xor(qi, 32);
    if (lane < 16) {
        if (mode == 0) {
            const float den = fmaxf(sqrtf(qr * qr + qi * qi), 1e-20f);
            wre[m] /= den; wim[m] /= den;
        } else {
            const float sc = sqrtf(wre[m] * wre[m] + wim[m] * wim[m]);
            qre[m] = qr * sc; qim[m] = qi * sc;
        }
    }
}

// ---------------------------------------------------------------------------
__global__ void presplit_k(const float* __restrict__ re, const float* __restrict__ im,
                           unsigned* __restrict__ Gh, unsigned* __restrict__ Gl) {
    const int e = blockIdx.x * 256 + threadIdx.x;
    unsigned h, l;
    split_pk(re[e], im[e], h, l);     // low16 = re (even K), high16 = im (odd K)
    Gh[e] = h; Gl[e] = l;
}

// Reduce PG partial images + presplit (pipe path)
__global__ void presplitP_k(const float* __restrict__ outP,
                            unsigned* __restrict__ Gh, unsigned* __restrict__ Gl) {
    const int e = blockIdx.x * 256 + threadIdx.x;
    float re = 0.f, im = 0.f;
    #pragma unroll
    for (int g = 0; g < PG; ++g) {
        re += outP[(size_t)g * (2 * MTOT) + e];
        im += outP[(size_t)g * (2 * MTOT) + MTOT + e];
    }
    unsigned h, l;
    split_pk(re, im, h, l);
    Gh[e] = h; Gl[e] = l;
}

// Reduce PG partial images -> final output
__global__ void reduceOut_k(const float* __restrict__ outP, float* __restrict__ out) {
    const int e = blockIdx.x * 256 + threadIdx.x;
    float re = 0.f, im = 0.f;
    #pragma unroll
    for (int g = 0; g < PG; ++g) {
        re += outP[(size_t)g * (2 * MTOT) + e];
        im += outP[(size_t)g * (2 * MTOT) + MTOT + e];
    }
    out[e] = re; out[MTOT + e] = im;
}

// ---------------------------------------------------------------------------
extern "C" void kernel_launch(void* const* d_in, const int* in_sizes, int n_in,
                              void* d_out, int out_size, void* d_ws, size_t ws_size,
                              hipStream_t stream)
{
    const float* xin  = (const float*)d_in[0];   // (2,192,192)
    const float* traj = (const float*)d_in[1];   // (36864,2)
    float* out = (float*)d_out;                  // (2,192,192)

    char* pb = (char*)d_ws;
    unsigned* BS = (unsigned*)pb; pb += (size_t)2304 * 6144 * 4;   // 56.6 MB
    unsigned* ES = (unsigned*)pb; pb += (size_t)2304 * 6144 * 4;   // 56.6 MB
    float* outP = (float*)pb; pb += (size_t)PG * 2 * MTOT * 4;
    float* wr   = (float*)pb; pb += MTOT * 4;
    float* wi   = (float*)pb; pb += MTOT * 4;
    float* dre  = (float*)pb; pb += MTOT * 4;
    float* dim_ = (float*)pb; pb += MTOT * 4;
    unsigned* Ghi = (unsigned*)pb; pb += MTOT * 4;
    unsigned* Glo = (unsigned*)pb; pb += MTOT * 4;

    precompP_k<<<dim3(MTOT / 256, NPIX), 256, 0, stream>>>(traj, 1, BS);
    winit_k<<<MTOT / 256, 256, 0, stream>>>(wr, wi);

    for (int it = 0; it < 3; ++it) {
        hipMemsetAsync(outP, 0, (size_t)PG * 2 * MTOT * 4, stream);
        ebuild_k<<<dim3(MTOT / 256, NPIX), 256, 0, stream>>>(traj, wr, wi, ES);
        adj_gemm_k<<<9 * SPLITS, 256, 0, stream>>>(ES, BS, outP);
        presplitP_k<<<MTOT / 256, 256, 0, stream>>>(outP, Ghi, Glo);
        fwdq_k<<<256, 576, 0, stream>>>(traj, Ghi, Glo, wr, wi, 0, dre, dim_);
    }

    presplit_k<<<MTOT / 256, 256, 0, stream>>>(xin, xin + MTOT, Ghi, Glo);
    fwdq_k<<<256, 576, 0, stream>>>(traj, Ghi, Glo, wr, wi, 1, dre, dim_);
    hipMemsetAsync(outP, 0, (size_t)PG * 2 * MTOT * 4, stream);
    ebuild_k<<<dim3(MTOT / 256, NPIX), 256, 0, stream>>>(traj, dre, dim_, ES);
    adj_gemm_k<<<9 * SPLITS, 256, 0, stream>>>(ES, BS, outP);
    reduceOut_k<<<MTOT / 256, 256, 0, stream>>>(outP, out);
}